// Round 10
// baseline (285.974 us; speedup 1.0000x reference)
//
#include <hip/hip_runtime.h>

#define H 128
#define BCAP 18432   // per-bucket edge capacity (mean 16384 + 16 sigma)

typedef __attribute__((ext_vector_type(8))) short bf16x8;
typedef __attribute__((ext_vector_type(4))) float f32x4;
typedef unsigned int uint;
typedef unsigned short ushort;

__device__ __forceinline__ ushort f2bf(float f) {
    uint u = __builtin_bit_cast(uint, f);
    uint r = u + 0x7FFFu + ((u >> 16) & 1u);
    return (ushort)(r >> 16);
}
__device__ __forceinline__ float bf_lo(uint u) {
    return __builtin_bit_cast(float, u << 16);
}
__device__ __forceinline__ float bf_hi(uint u) {
    return __builtin_bit_cast(float, u & 0xFFFF0000u);
}

// =======================================================================
// CSR build v3: fixed-capacity buckets, 2 kernels.
// =======================================================================

__global__ void scatter_direct(const int* __restrict__ ei, int E, int NB,
                               int* __restrict__ gcnt, int2* __restrict__ ebuf) {
    __shared__ int cnt[1024];
    __shared__ int base[1024];
    int blk = blockIdx.x, t = threadIdx.x;
    for (int b = t; b < NB; b += 256) cnt[b] = 0;
    __syncthreads();
    int lo = blk << 12, hi = min(lo + 4096, E);
    for (int e = lo + t; e < hi; e += 256) atomicAdd(&cnt[ei[e] >> 10], 1);
    __syncthreads();
    for (int b = t; b < NB; b += 256) {
        int c = cnt[b];
        base[b] = c ? atomicAdd(&gcnt[b * 16], c) : 0;
        cnt[b] = 0;
    }
    __syncthreads();
    for (int e = lo + t; e < hi; e += 256) {
        int r = ei[e], c = ei[E + e];
        int b = r >> 10;
        int pos = base[b] + atomicAdd(&cnt[b], 1);
        if (pos < BCAP) ebuf[(size_t)b * BCAP + pos] = make_int2(r, c);
    }
}

__global__ __launch_bounds__(1024)
void bucket_csr2(const int2* __restrict__ ebuf, const int* __restrict__ gcnt,
                 int NB, int N, int* __restrict__ deg, int* __restrict__ off,
                 int* __restrict__ colss) {
    __shared__ int rcnt[1024], rloff[1024];
    int b = blockIdx.x, t = threadIdx.x;
    int rowbase = b << 10;
    int ebase = b * BCAP;
    int ne = min(gcnt[b * 16], BCAP);
    rcnt[t] = 0;
    __syncthreads();
    for (int e = t; e < ne; e += 1024) atomicAdd(&rcnt[ebuf[(size_t)ebase + e].x - rowbase], 1);
    __syncthreads();
    int v = rcnt[t];
    rloff[t] = v;
    __syncthreads();
    for (int d = 1; d < 1024; d <<= 1) {
        int u = (t >= d) ? rloff[t - d] : 0;
        __syncthreads();
        rloff[t] += u;
        __syncthreads();
    }
    int ex = rloff[t] - v;
    int row = rowbase + t;
    if (row < N) {
        deg[row] = v;
        off[row] = ebase + ex;
    }
    __syncthreads();
    rloff[t] = ex;
    rcnt[t] = 0;
    __syncthreads();
    for (int e = t; e < ne; e += 1024) {
        int2 rc = ebuf[(size_t)ebase + e];
        int lr = rc.x - rowbase;
        int pz = atomicAdd(&rcnt[lr], 1);
        colss[ebase + rloff[lr] + pz] = rc.y;
    }
}

// c_i[k] = sum_j W3[i][k][j] * relu(W4[i][j])
__global__ void cvec_kernel(const float* __restrict__ W3, const float* __restrict__ W4,
                            float* __restrict__ cvec) {
    int i = blockIdx.x, k = threadIdx.x;
    const float* w3 = W3 + i * H * H + k * H;
    const float* w4 = W4 + i * H;
    float s = 0.f;
    for (int j = 0; j < H; ++j) s += w3[j] * fmaxf(w4[j], 0.f);
    cvec[i * H + k] = s;
}

__global__ void cast_bf16(const float* __restrict__ in, ushort* __restrict__ outp, int n8) {
    int i = blockIdx.x * blockDim.x + threadIdx.x;
    if (i >= n8) return;
    const float4* in4 = (const float4*)in;
    float4 a = in4[2 * i], b = in4[2 * i + 1];
    uint4 o;
    o.x = (uint)f2bf(a.x) | ((uint)f2bf(a.y) << 16);
    o.y = (uint)f2bf(a.z) | ((uint)f2bf(a.w) << 16);
    o.z = (uint)f2bf(b.x) | ((uint)f2bf(b.y) << 16);
    o.w = (uint)f2bf(b.z) | ((uint)f2bf(b.w) << 16);
    ((uint4*)outp)[i] = o;
}

// =======================================================================
// gemm_pairs v2: C[n][j] = sum_pr sum_k A_pr[n][k]*W_pr[j][k]
//                (+deg*cvec) (+relu)
// Pipelined: stage chunk c+1 into REGISTERS while computing chunk c from
// LDS (hides HBM latency under MFMA). LDS [128 r][8 slot] uint4 with
// slot^(r&7) swizzle (<=2-way = free). CAST0: pair0 staged from f32 with
// in-register bf16 convert + write-through to xbout.
// =======================================================================

template<int RELU, int OUT_BF16, int CAST0>
__global__ __launch_bounds__(256)
void gemm_pairs(const void* __restrict__ A0, const ushort* __restrict__ W0,
                const ushort* __restrict__ A1, const ushort* __restrict__ W1p,
                int npairs, const int* __restrict__ deg, const float* __restrict__ cvec,
                void* __restrict__ Cout, ushort* __restrict__ xbout, int N)
{
    __shared__ uint4 A4[1024];
    __shared__ uint4 W4[1024];
    int t = threadIdx.x;
    int w = t >> 6, l = t & 63;
    int lg = l >> 4, lr = l & 15;
    int rowBase = blockIdx.x * 128;

    f32x4 acc[2][8];
#pragma unroll
    for (int rt = 0; rt < 2; ++rt)
#pragma unroll
        for (int ct = 0; ct < 8; ++ct) acc[rt][ct] = (f32x4){0.f, 0.f, 0.f, 0.f};

    uint4 ar[4], wr[4];
    int nc = npairs * 2;

    // stage chunk c (pr=c>>1, kc=c&1) into registers
    auto stage = [&](int c) {
        int pr = c >> 1, kc = c & 1;
        const uint4* Ag = (const uint4*)(pr ? (const void*)A1 : A0);
        const uint4* Wg = (const uint4*)(pr ? W1p : W0);
#pragma unroll
        for (int it = 0; it < 4; ++it) {
            int idx = it * 256 + t;
            int r = idx >> 3, s = idx & 7;
            int gr = rowBase + r;
            uint4 v = make_uint4(0, 0, 0, 0);
            if (CAST0 && pr == 0) {
                if (gr < N) {
                    const float4* xg = (const float4*)A0;
                    float4 a = xg[(size_t)gr * 32 + (kc * 8 + s) * 2];
                    float4 b = xg[(size_t)gr * 32 + (kc * 8 + s) * 2 + 1];
                    v.x = (uint)f2bf(a.x) | ((uint)f2bf(a.y) << 16);
                    v.y = (uint)f2bf(a.z) | ((uint)f2bf(a.w) << 16);
                    v.z = (uint)f2bf(b.x) | ((uint)f2bf(b.y) << 16);
                    v.w = (uint)f2bf(b.z) | ((uint)f2bf(b.w) << 16);
                    ((uint4*)xbout)[(size_t)gr * 16 + kc * 8 + s] = v;
                }
            } else {
                if (gr < N) v = Ag[(size_t)gr * 16 + kc * 8 + s];
            }
            ar[it] = v;
            wr[it] = Wg[r * 16 + kc * 8 + s];
        }
    };
    auto commit = [&]() {
#pragma unroll
        for (int it = 0; it < 4; ++it) {
            int idx = it * 256 + t;
            int r = idx >> 3, s = idx & 7;
            A4[r * 8 + (s ^ (r & 7))] = ar[it];
            W4[r * 8 + (s ^ (r & 7))] = wr[it];
        }
    };

    stage(0);
    commit();
    __syncthreads();

    for (int c = 0; c < nc; ++c) {
        if (c + 1 < nc) stage(c + 1);      // global loads in flight during compute
#pragma unroll
        for (int kk = 0; kk < 2; ++kk) {
            int slot = kk * 4 + lg;
            bf16x8 af[2], bfr[8];
#pragma unroll
            for (int rt = 0; rt < 2; ++rt) {
                int r = w * 32 + rt * 16 + lr;
                af[rt] = *(const bf16x8*)&A4[r * 8 + (slot ^ (r & 7))];
            }
#pragma unroll
            for (int ct = 0; ct < 8; ++ct) {
                int r = ct * 16 + lr;
                bfr[ct] = *(const bf16x8*)&W4[r * 8 + (slot ^ (r & 7))];
            }
#pragma unroll
            for (int rt = 0; rt < 2; ++rt)
#pragma unroll
                for (int ct = 0; ct < 8; ++ct)
                    acc[rt][ct] = __builtin_amdgcn_mfma_f32_16x16x32_bf16(
                        af[rt], bfr[ct], acc[rt][ct], 0, 0, 0);
        }
        __syncthreads();                    // all waves done reading LDS
        if (c + 1 < nc) {
            commit();                       // overwrite LDS with next chunk
            __syncthreads();
        }
    }

    float cv[8];
#pragma unroll
    for (int ct = 0; ct < 8; ++ct) cv[ct] = cvec[ct * 16 + lr];
#pragma unroll
    for (int rt = 0; rt < 2; ++rt) {
#pragma unroll
        for (int j = 0; j < 4; ++j) {
            int gr = rowBase + w * 32 + rt * 16 + lg * 4 + j;
            if (gr < N) {
                float d = (float)deg[gr];
#pragma unroll
                for (int ct = 0; ct < 8; ++ct) {
                    int gc = ct * 16 + lr;
                    float v = acc[rt][ct][j] + d * cv[ct];
                    if (RELU) v = fmaxf(v, 0.f);
                    if (OUT_BF16) ((ushort*)Cout)[(size_t)gr * H + gc] = f2bf(v);
                    else ((float*)Cout)[(size_t)gr * H + gc] = v;
                }
            }
        }
    }
}

// =======================================================================
// aggregate_sum (R8 form): s[n] = sum_{e in row n} h[cols[e]]
// one wave per node; wave-uniform cols base (scalar-load friendly);
// 8-deep gather unroll. Bucket-gapped CSR: range = off[n] .. off[n]+deg[n].
// =======================================================================

__global__ void aggregate_sum(const ushort* __restrict__ hsrc,
                              const int* __restrict__ off, const int* __restrict__ deg,
                              const int* __restrict__ cols,
                              ushort* __restrict__ sdst, int N)
{
    int node = blockIdx.x * 4 + (threadIdx.x >> 6);
    if (node >= N) return;
    int l = threadIdx.x & 63;
    int s = off[node], e = s + deg[node];
    const uint* pu = (const uint*)hsrc;  // [N][64]
    float ax = 0.f, ay = 0.f;
    int i = s;
    for (; i + 8 <= e; i += 8) {
        uint v0 = pu[(size_t)cols[i]     * 64 + l];
        uint v1 = pu[(size_t)cols[i + 1] * 64 + l];
        uint v2 = pu[(size_t)cols[i + 2] * 64 + l];
        uint v3 = pu[(size_t)cols[i + 3] * 64 + l];
        uint v4 = pu[(size_t)cols[i + 4] * 64 + l];
        uint v5 = pu[(size_t)cols[i + 5] * 64 + l];
        uint v6 = pu[(size_t)cols[i + 6] * 64 + l];
        uint v7 = pu[(size_t)cols[i + 7] * 64 + l];
        ax += bf_lo(v0) + bf_lo(v1) + bf_lo(v2) + bf_lo(v3)
            + bf_lo(v4) + bf_lo(v5) + bf_lo(v6) + bf_lo(v7);
        ay += bf_hi(v0) + bf_hi(v1) + bf_hi(v2) + bf_hi(v3)
            + bf_hi(v4) + bf_hi(v5) + bf_hi(v6) + bf_hi(v7);
    }
    for (; i + 4 <= e; i += 4) {
        uint v0 = pu[(size_t)cols[i]     * 64 + l];
        uint v1 = pu[(size_t)cols[i + 1] * 64 + l];
        uint v2 = pu[(size_t)cols[i + 2] * 64 + l];
        uint v3 = pu[(size_t)cols[i + 3] * 64 + l];
        ax += bf_lo(v0) + bf_lo(v1) + bf_lo(v2) + bf_lo(v3);
        ay += bf_hi(v0) + bf_hi(v1) + bf_hi(v2) + bf_hi(v3);
    }
    for (; i < e; ++i) {
        uint v = pu[(size_t)cols[i] * 64 + l];
        ax += bf_lo(v);
        ay += bf_hi(v);
    }
    ((uint*)sdst)[(size_t)node * 64 + l] = (uint)f2bf(ax) | ((uint)f2bf(ay) << 16);
}

// =======================================================================
// launch
// =======================================================================

extern "C" void kernel_launch(void* const* d_in, const int* in_sizes, int n_in,
                              void* d_out, int out_size, void* d_ws, size_t ws_size,
                              hipStream_t stream)
{
    const float* x  = (const float*)d_in[0];
    const int*   ei = (const int*)d_in[1];
    const float* W1 = (const float*)d_in[2];
    const float* W2 = (const float*)d_in[3];
    const float* W3 = (const float*)d_in[4];
    const float* W4 = (const float*)d_in[5];
    int N   = in_sizes[0] / H;
    int E   = in_sizes[1] / 2;
    int HOP = in_sizes[2] / (H * H);

    int NB   = (N + 1023) >> 10;
    int NBLK = (E + 4095) >> 12;

    char* ws = (char*)d_ws;
    int*   gcnt  = (int*)ws;                  // NB*16 (line-padded)
    int*   deg   = gcnt + NB * 16;            // N
    int*   off   = deg + N;                   // N
    int*   colss = off + N;                   // NB*BCAP
    float* cvec  = (float*)(colss + (size_t)NB * BCAP);   // HOP*H
    size_t fo = (((size_t)((char*)(cvec + HOP * H) - ws)) + 255) & ~(size_t)255;
    int2*  ebuf  = (int2*)(ws + fo);          // NB*BCAP int2
    ushort* W1b  = (ushort*)(ebuf + (size_t)NB * BCAP);   // HOP*H*H
    ushort* W2b  = W1b + (size_t)HOP * H * H; // HOP*H*H
    ushort* xb   = W2b + (size_t)HOP * H * H; // N*H
    ushort* h    = xb + (size_t)N * H;        // N*H
    ushort* sagg = h + (size_t)N * H;         // N*H

    // ---- CSR build (2 kernels) ----
    hipMemsetAsync(gcnt, 0, sizeof(int) * NB * 16, stream);
    scatter_direct<<<NBLK, 256, 0, stream>>>(ei, E, NB, gcnt, ebuf);
    bucket_csr2<<<NB, 1024, 0, stream>>>(ebuf, gcnt, NB, N, deg, off, colss);

    cvec_kernel<<<HOP, H, 0, stream>>>(W3, W4, cvec);

    // ---- weight casts (tiny) ----
    int nw8 = HOP * H * H / 8;
    cast_bf16<<<(nw8 + 255) / 256, 256, 0, stream>>>(W1, W1b, nw8);
    cast_bf16<<<(nw8 + 255) / 256, 256, 0, stream>>>(W2, W2b, nw8);

    int gblocks = (N + 127) / 128;
    float* out = (float*)d_out;

    // hop 0: h = relu(x@W1[0]^T + deg*c0), fused f32->bf16 cast writes xb
    if (HOP == 1) {
        gemm_pairs<1, 0, 1><<<gblocks, 256, 0, stream>>>(x, W1b, nullptr, nullptr, 1,
                                                         deg, cvec, out, xb, N);
        return;
    }
    gemm_pairs<1, 1, 1><<<gblocks, 256, 0, stream>>>(x, W1b, nullptr, nullptr, 1,
                                                     deg, cvec, h, xb, N);

    for (int i = 1; i < HOP; ++i) {
        int last = (i == HOP - 1);
        // sagg = A . h
        aggregate_sum<<<(N + 3) / 4, 256, 0, stream>>>(h, off, deg, colss, sagg, N);
        // dst = relu(xb@W1[i]^T + sagg@W2[i]^T + deg*c_i)
        if (last)
            gemm_pairs<1, 0, 0><<<gblocks, 256, 0, stream>>>(xb, W1b + (size_t)i * H * H,
                                                             sagg, W2b + (size_t)i * H * H,
                                                             2, deg, cvec + i * H, out,
                                                             nullptr, N);
        else
            gemm_pairs<1, 1, 0><<<gblocks, 256, 0, stream>>>(xb, W1b + (size_t)i * H * H,
                                                             sagg, W2b + (size_t)i * H * H,
                                                             2, deg, cvec + i * H, h,
                                                             nullptr, N);
    }
}

// Round 11
// 253.960 us; speedup vs baseline: 1.1261x; 1.1261x over previous
//
#include <hip/hip_runtime.h>

#define H 128
#define BCAP 18432   // per-bucket edge capacity (mean 16384 + 16 sigma)

typedef __attribute__((ext_vector_type(8))) short bf16x8;
typedef __attribute__((ext_vector_type(4))) float f32x4;
typedef unsigned int uint;
typedef unsigned short ushort;

__device__ __forceinline__ ushort f2bf(float f) {
    uint u = __builtin_bit_cast(uint, f);
    uint r = u + 0x7FFFu + ((u >> 16) & 1u);
    return (ushort)(r >> 16);
}
__device__ __forceinline__ float bf_lo(uint u) {
    return __builtin_bit_cast(float, u << 16);
}
__device__ __forceinline__ float bf_hi(uint u) {
    return __builtin_bit_cast(float, u & 0xFFFF0000u);
}

// =======================================================================
// CSR build v3: fixed-capacity buckets, 2 kernels.
// =======================================================================

__global__ void scatter_direct(const int* __restrict__ ei, int E, int NB,
                               int* __restrict__ gcnt, int2* __restrict__ ebuf) {
    __shared__ int cnt[1024];
    __shared__ int base[1024];
    int blk = blockIdx.x, t = threadIdx.x;
    for (int b = t; b < NB; b += 256) cnt[b] = 0;
    __syncthreads();
    int lo = blk << 12, hi = min(lo + 4096, E);
    for (int e = lo + t; e < hi; e += 256) atomicAdd(&cnt[ei[e] >> 10], 1);
    __syncthreads();
    for (int b = t; b < NB; b += 256) {
        int c = cnt[b];
        base[b] = c ? atomicAdd(&gcnt[b * 16], c) : 0;
        cnt[b] = 0;
    }
    __syncthreads();
    for (int e = lo + t; e < hi; e += 256) {
        int r = ei[e], c = ei[E + e];
        int b = r >> 10;
        int pos = base[b] + atomicAdd(&cnt[b], 1);
        if (pos < BCAP) ebuf[(size_t)b * BCAP + pos] = make_int2(r, c);
    }
}

__global__ __launch_bounds__(1024)
void bucket_csr2(const int2* __restrict__ ebuf, const int* __restrict__ gcnt,
                 int NB, int N, int* __restrict__ deg, int* __restrict__ off,
                 int* __restrict__ colss) {
    __shared__ int rcnt[1024], rloff[1024];
    int b = blockIdx.x, t = threadIdx.x;
    int rowbase = b << 10;
    int ebase = b * BCAP;
    int ne = min(gcnt[b * 16], BCAP);
    rcnt[t] = 0;
    __syncthreads();
    for (int e = t; e < ne; e += 1024) atomicAdd(&rcnt[ebuf[(size_t)ebase + e].x - rowbase], 1);
    __syncthreads();
    int v = rcnt[t];
    rloff[t] = v;
    __syncthreads();
    for (int d = 1; d < 1024; d <<= 1) {
        int u = (t >= d) ? rloff[t - d] : 0;
        __syncthreads();
        rloff[t] += u;
        __syncthreads();
    }
    int ex = rloff[t] - v;
    int row = rowbase + t;
    if (row < N) {
        deg[row] = v;
        off[row] = ebase + ex;
    }
    __syncthreads();
    rloff[t] = ex;
    rcnt[t] = 0;
    __syncthreads();
    for (int e = t; e < ne; e += 1024) {
        int2 rc = ebuf[(size_t)ebase + e];
        int lr = rc.x - rowbase;
        int pz = atomicAdd(&rcnt[lr], 1);
        colss[ebase + rloff[lr] + pz] = rc.y;
    }
}

// c_i[k] = sum_j W3[i][k][j] * relu(W4[i][j])
__global__ void cvec_kernel(const float* __restrict__ W3, const float* __restrict__ W4,
                            float* __restrict__ cvec) {
    int i = blockIdx.x, k = threadIdx.x;
    const float* w3 = W3 + i * H * H + k * H;
    const float* w4 = W4 + i * H;
    float s = 0.f;
    for (int j = 0; j < H; ++j) s += w3[j] * fmaxf(w4[j], 0.f);
    cvec[i * H + k] = s;
}

// casts both weight tensors in one launch (dst W1b, W2b are contiguous)
__global__ void cast_w(const float* __restrict__ W1, const float* __restrict__ W2,
                       ushort* __restrict__ outp, int n8) {
    int i = blockIdx.x * blockDim.x + threadIdx.x;
    if (i >= 2 * n8) return;
    const float4* in4 = (const float4*)((i < n8) ? W1 : W2);
    int j = (i < n8) ? i : i - n8;
    float4 a = in4[2 * j], b = in4[2 * j + 1];
    uint4 o;
    o.x = (uint)f2bf(a.x) | ((uint)f2bf(a.y) << 16);
    o.y = (uint)f2bf(a.z) | ((uint)f2bf(a.w) << 16);
    o.z = (uint)f2bf(b.x) | ((uint)f2bf(b.y) << 16);
    o.w = (uint)f2bf(b.z) | ((uint)f2bf(b.w) << 16);
    ((uint4*)outp)[i] = o;
}

// =======================================================================
// gemm_pairs v3: 256-row x 128-col tile, 512 threads (8 waves), direct
// LDS staging (R8-proven), 2 barriers per K-64 chunk, 2x MFMA per barrier
// vs the 128-tile. LDS A 64KB + W 16KB = 80KB -> 2 blocks/CU.
// slot^(r&7) swizzle -> <=2-way bank aliasing (free).
// CAST0: pair0 A is f32 x, converted during staging, written through xbout.
// =======================================================================

template<int RELU, int OUT_BF16, int CAST0>
__global__ __launch_bounds__(512)
void gemm_pairs(const void* __restrict__ A0, const ushort* __restrict__ W0,
                const ushort* __restrict__ A1, const ushort* __restrict__ W1p,
                int npairs, const int* __restrict__ deg, const float* __restrict__ cvec,
                void* __restrict__ Cout, ushort* __restrict__ xbout, int N)
{
    __shared__ uint4 A4[2048];   // 256 rows x 8 slots
    __shared__ uint4 W4[1024];   // 128 rows x 8 slots
    int t = threadIdx.x;
    int w = t >> 6, l = t & 63;
    int lg = l >> 4, lr = l & 15;
    int rowBase = blockIdx.x * 256;

    f32x4 acc[2][8];
#pragma unroll
    for (int rt = 0; rt < 2; ++rt)
#pragma unroll
        for (int ct = 0; ct < 8; ++ct) acc[rt][ct] = (f32x4){0.f, 0.f, 0.f, 0.f};

    for (int pr = 0; pr < npairs; ++pr) {
        const uint4* Ag = (const uint4*)(pr ? (const void*)A1 : A0);
        const uint4* Wg = (const uint4*)(pr ? W1p : W0);
        for (int kc = 0; kc < 2; ++kc) {
            if (pr || kc) __syncthreads();
            // stage A: 2048 uint4
#pragma unroll
            for (int it = 0; it < 4; ++it) {
                int idx = it * 512 + t;
                int r = idx >> 3, s = idx & 7;
                int gr = rowBase + r;
                uint4 v = make_uint4(0, 0, 0, 0);
                if (CAST0 && pr == 0) {
                    if (gr < N) {
                        const float4* xg = (const float4*)A0;
                        float4 a = xg[(size_t)gr * 32 + (kc * 8 + s) * 2];
                        float4 b = xg[(size_t)gr * 32 + (kc * 8 + s) * 2 + 1];
                        v.x = (uint)f2bf(a.x) | ((uint)f2bf(a.y) << 16);
                        v.y = (uint)f2bf(a.z) | ((uint)f2bf(a.w) << 16);
                        v.z = (uint)f2bf(b.x) | ((uint)f2bf(b.y) << 16);
                        v.w = (uint)f2bf(b.z) | ((uint)f2bf(b.w) << 16);
                        ((uint4*)xbout)[(size_t)gr * 16 + kc * 8 + s] = v;
                    }
                } else {
                    if (gr < N) v = Ag[(size_t)gr * 16 + kc * 8 + s];
                }
                A4[r * 8 + (s ^ (r & 7))] = v;
            }
            // stage W: 1024 uint4
#pragma unroll
            for (int it = 0; it < 2; ++it) {
                int idx = it * 512 + t;
                int r = idx >> 3, s = idx & 7;
                W4[r * 8 + (s ^ (r & 7))] = Wg[r * 16 + kc * 8 + s];
            }
            __syncthreads();
#pragma unroll
            for (int kk = 0; kk < 2; ++kk) {
                int slot = kk * 4 + lg;
                bf16x8 af[2], bfr[8];
#pragma unroll
                for (int rt = 0; rt < 2; ++rt) {
                    int r = w * 32 + rt * 16 + lr;
                    af[rt] = *(const bf16x8*)&A4[r * 8 + (slot ^ (r & 7))];
                }
#pragma unroll
                for (int ct = 0; ct < 8; ++ct) {
                    int r = ct * 16 + lr;
                    bfr[ct] = *(const bf16x8*)&W4[r * 8 + (slot ^ (r & 7))];
                }
#pragma unroll
                for (int rt = 0; rt < 2; ++rt)
#pragma unroll
                    for (int ct = 0; ct < 8; ++ct)
                        acc[rt][ct] = __builtin_amdgcn_mfma_f32_16x16x32_bf16(
                            af[rt], bfr[ct], acc[rt][ct], 0, 0, 0);
            }
        }
    }

    float cv[8];
#pragma unroll
    for (int ct = 0; ct < 8; ++ct) cv[ct] = cvec[ct * 16 + lr];
#pragma unroll
    for (int rt = 0; rt < 2; ++rt) {
#pragma unroll
        for (int j = 0; j < 4; ++j) {
            int gr = rowBase + w * 32 + rt * 16 + lg * 4 + j;
            if (gr < N) {
                float d = (float)deg[gr];
#pragma unroll
                for (int ct = 0; ct < 8; ++ct) {
                    int gc = ct * 16 + lr;
                    float v = acc[rt][ct][j] + d * cv[ct];
                    if (RELU) v = fmaxf(v, 0.f);
                    if (OUT_BF16) ((ushort*)Cout)[(size_t)gr * H + gc] = f2bf(v);
                    else ((float*)Cout)[(size_t)gr * H + gc] = v;
                }
            }
        }
    }
}

// =======================================================================
// aggregate_sum (R8 form, measured floor ~61us @3.4TB/s):
// s[n] = sum_{e in row n} h[cols[e]]; one wave per node; wave-uniform
// cols base; 8-deep gather unroll. CSR range = off[n] .. off[n]+deg[n].
// =======================================================================

__global__ void aggregate_sum(const ushort* __restrict__ hsrc,
                              const int* __restrict__ off, const int* __restrict__ deg,
                              const int* __restrict__ cols,
                              ushort* __restrict__ sdst, int N)
{
    int node = blockIdx.x * 4 + (threadIdx.x >> 6);
    if (node >= N) return;
    int l = threadIdx.x & 63;
    int s = off[node], e = s + deg[node];
    const uint* pu = (const uint*)hsrc;  // [N][64]
    float ax = 0.f, ay = 0.f;
    int i = s;
    for (; i + 8 <= e; i += 8) {
        uint v0 = pu[(size_t)cols[i]     * 64 + l];
        uint v1 = pu[(size_t)cols[i + 1] * 64 + l];
        uint v2 = pu[(size_t)cols[i + 2] * 64 + l];
        uint v3 = pu[(size_t)cols[i + 3] * 64 + l];
        uint v4 = pu[(size_t)cols[i + 4] * 64 + l];
        uint v5 = pu[(size_t)cols[i + 5] * 64 + l];
        uint v6 = pu[(size_t)cols[i + 6] * 64 + l];
        uint v7 = pu[(size_t)cols[i + 7] * 64 + l];
        ax += bf_lo(v0) + bf_lo(v1) + bf_lo(v2) + bf_lo(v3)
            + bf_lo(v4) + bf_lo(v5) + bf_lo(v6) + bf_lo(v7);
        ay += bf_hi(v0) + bf_hi(v1) + bf_hi(v2) + bf_hi(v3)
            + bf_hi(v4) + bf_hi(v5) + bf_hi(v6) + bf_hi(v7);
    }
    for (; i + 4 <= e; i += 4) {
        uint v0 = pu[(size_t)cols[i]     * 64 + l];
        uint v1 = pu[(size_t)cols[i + 1] * 64 + l];
        uint v2 = pu[(size_t)cols[i + 2] * 64 + l];
        uint v3 = pu[(size_t)cols[i + 3] * 64 + l];
        ax += bf_lo(v0) + bf_lo(v1) + bf_lo(v2) + bf_lo(v3);
        ay += bf_hi(v0) + bf_hi(v1) + bf_hi(v2) + bf_hi(v3);
    }
    for (; i < e; ++i) {
        uint v = pu[(size_t)cols[i] * 64 + l];
        ax += bf_lo(v);
        ay += bf_hi(v);
    }
    ((uint*)sdst)[(size_t)node * 64 + l] = (uint)f2bf(ax) | ((uint)f2bf(ay) << 16);
}

// =======================================================================
// launch
// =======================================================================

extern "C" void kernel_launch(void* const* d_in, const int* in_sizes, int n_in,
                              void* d_out, int out_size, void* d_ws, size_t ws_size,
                              hipStream_t stream)
{
    const float* x  = (const float*)d_in[0];
    const int*   ei = (const int*)d_in[1];
    const float* W1 = (const float*)d_in[2];
    const float* W2 = (const float*)d_in[3];
    const float* W3 = (const float*)d_in[4];
    const float* W4 = (const float*)d_in[5];
    int N   = in_sizes[0] / H;
    int E   = in_sizes[1] / 2;
    int HOP = in_sizes[2] / (H * H);

    int NB   = (N + 1023) >> 10;
    int NBLK = (E + 4095) >> 12;

    char* ws = (char*)d_ws;
    int*   gcnt  = (int*)ws;                  // NB*16 (line-padded)
    int*   deg   = gcnt + NB * 16;            // N
    int*   off   = deg + N;                   // N
    int*   colss = off + N;                   // NB*BCAP
    float* cvec  = (float*)(colss + (size_t)NB * BCAP);   // HOP*H
    size_t fo = (((size_t)((char*)(cvec + HOP * H) - ws)) + 255) & ~(size_t)255;
    int2*  ebuf  = (int2*)(ws + fo);          // NB*BCAP int2
    ushort* W1b  = (ushort*)(ebuf + (size_t)NB * BCAP);   // HOP*H*H
    ushort* W2b  = W1b + (size_t)HOP * H * H; // HOP*H*H (contiguous after W1b)
    ushort* xb   = W2b + (size_t)HOP * H * H; // N*H
    ushort* h    = xb + (size_t)N * H;        // N*H
    ushort* sagg = h + (size_t)N * H;         // N*H

    // ---- CSR build (2 kernels) ----
    hipMemsetAsync(gcnt, 0, sizeof(int) * NB * 16, stream);
    scatter_direct<<<NBLK, 256, 0, stream>>>(ei, E, NB, gcnt, ebuf);
    bucket_csr2<<<NB, 1024, 0, stream>>>(ebuf, gcnt, NB, N, deg, off, colss);

    cvec_kernel<<<HOP, H, 0, stream>>>(W3, W4, cvec);

    // ---- weight casts (one launch) ----
    int nw8 = HOP * H * H / 8;
    cast_w<<<(2 * nw8 + 255) / 256, 256, 0, stream>>>(W1, W2, W1b, nw8);

    int gblocks = (N + 255) / 256;
    float* out = (float*)d_out;

    // hop 0: h = relu(x@W1[0]^T + deg*c0), fused f32->bf16 cast writes xb
    if (HOP == 1) {
        gemm_pairs<1, 0, 1><<<gblocks, 512, 0, stream>>>(x, W1b, nullptr, nullptr, 1,
                                                         deg, cvec, out, xb, N);
        return;
    }
    gemm_pairs<1, 1, 1><<<gblocks, 512, 0, stream>>>(x, W1b, nullptr, nullptr, 1,
                                                     deg, cvec, h, xb, N);

    for (int i = 1; i < HOP; ++i) {
        int last = (i == HOP - 1);
        // sagg = A . h
        aggregate_sum<<<(N + 3) / 4, 256, 0, stream>>>(h, off, deg, colss, sagg, N);
        // dst = relu(xb@W1[i]^T + sagg@W2[i]^T + deg*c_i)
        if (last)
            gemm_pairs<1, 0, 0><<<gblocks, 512, 0, stream>>>(xb, W1b + (size_t)i * H * H,
                                                             sagg, W2b + (size_t)i * H * H,
                                                             2, deg, cvec + i * H, out,
                                                             nullptr, N);
        else
            gemm_pairs<1, 1, 0><<<gblocks, 512, 0, stream>>>(xb, W1b + (size_t)i * H * H,
                                                             sagg, W2b + (size_t)i * H * H,
                                                             2, deg, cvec + i * H, h,
                                                             nullptr, N);
    }
}